// Round 15
// baseline (352.330 us; speedup 1.0000x reference)
//
#include <hip/hip_runtime.h>
#include <hip/hip_bf16.h>

typedef __bf16 bf16;
typedef __bf16 bf16x4 __attribute__((ext_vector_type(4)));
typedef __bf16 bf16x8 __attribute__((ext_vector_type(8)));
typedef float  f32x4  __attribute__((ext_vector_type(4)));

#define B_  4
#define N_  2048
#define D_  1024
#define H_  16
#define HD_ 64

// 0.125 (1/sqrt(64)) * log2(e): folded into Wq during transpose
#define QSCALE 0.1803368801111204f

__device__ __forceinline__ bf16x8 ld8(const bf16* p) {
  return *reinterpret_cast<const bf16x8*>(p);
}

// raw v_exp_f32 (2^x): no denormal-fixup sequence; -1e30 -> 0, handled in HW
__device__ __forceinline__ float exp2_raw(float x) {
  float y;
  asm("v_exp_f32 %0, %1" : "=v"(y) : "v"(x));
  return y;
}

// async global->LDS, 16B per lane; lds base must be wave-uniform
__device__ __forceinline__ void gload16(const bf16* g, bf16* l) {
  __builtin_amdgcn_global_load_lds(
      (const __attribute__((address_space(1))) void*)g,
      (__attribute__((address_space(3))) void*)l, 16, 0, 0);
}

// ---------------- f32 -> bf16 cast (8 elems/thread) ----------------------------
__global__ __launch_bounds__(256) void cast_k(const float* __restrict__ in,
                                              bf16* __restrict__ out, int n) {
  int i = (blockIdx.x * 256 + threadIdx.x) * 8;
  if (i >= n) return;
  float4 a = *reinterpret_cast<const float4*>(in + i);
  float4 b = *reinterpret_cast<const float4*>(in + i + 4);
  bf16x8 o;
  o[0] = (bf16)a.x; o[1] = (bf16)a.y; o[2] = (bf16)a.z; o[3] = (bf16)a.w;
  o[4] = (bf16)b.x; o[5] = (bf16)b.y; o[6] = (bf16)b.z; o[7] = (bf16)b.w;
  *reinterpret_cast<bf16x8*>(out + i) = o;
}

// ---- fused transpose-cast of Wq/Wk/Wv (z selects): out[z][c][r] = s*in[z][r][c]
__global__ __launch_bounds__(1024)
void transpose3_k(const float* __restrict__ w0, const float* __restrict__ w1,
                  const float* __restrict__ w2, bf16* __restrict__ out) {
  __shared__ float t[32][33];
  const int z = blockIdx.z;
  const float* in = (z == 0) ? w0 : (z == 1) ? w1 : w2;
  const float scale = (z == 0) ? QSCALE : 1.0f;
  bf16* o = out + (size_t)z * D_ * D_;
  int c = blockIdx.x * 32 + threadIdx.x;
  int r = blockIdx.y * 32 + threadIdx.y;
  t[threadIdx.y][threadIdx.x] = in[r * D_ + c];
  __syncthreads();
  int oc = blockIdx.y * 32 + threadIdx.x;
  int orr = blockIdx.x * 32 + threadIdx.y;
  o[orr * D_ + oc] = (bf16)(scale * t[threadIdx.x][threadIdx.y]);
}

// ---------------- fused QKV GEMM: [8192,1024] x [3072,1024]^T ------------------
// 256x128 tile, 8 waves (512 thr), double-buffered counted-vmcnt(3).
// LDS 48 KB -> 3 blocks/CU = 6 waves/SIMD; grid 768 = exactly 3x256 (full fill).
// Per iter: barrierA -> stage(t+1) 3 loads/thr -> vmcnt(3) -> barrierB -> compute.
__global__ __launch_bounds__(512, 6)
void gemm_qkv(const bf16* __restrict__ A, const bf16* __restrict__ Bt,
              bf16* __restrict__ qb, bf16* __restrict__ kb, bf16* __restrict__ vtb)
{
  __shared__ bf16 As[2 * 256 * 32];   // 32 KB
  __shared__ bf16 Bs[2 * 128 * 32];   // 16 KB
  const int tid  = threadIdx.x;
  const int lane = tid & 63;
  const int wid  = tid >> 6;                // 0..7
  const int wg   = blockIdx.x;
  const int xcd  = wg & 7;
  const int idx  = wg >> 3;                 // 0..95
  const int brow = ((xcd << 2) + (idx & 3)) * 256;
  const int bcol = (idx >> 2) * 128;        // 0..23 blocks
  const int wr   = (wid >> 1) * 64;         // 0..192
  const int wc   = (wid & 1) * 64;          // 0,64
  const int l15  = lane & 15;
  const int g    = lane >> 4;

  f32x4 acc[4][4] = {};
  const int srow = wid * 16 + (lane >> 2);                 // staged row (+j*128)
  const int schk = ((lane & 3) ^ ((lane >> 4) & 3)) * 8;   // swz src col (elems)
  const int q8   = ((lane >> 4) ^ (l15 >> 2)) * 8;         // swz read col

  // prologue: stage tile 0 into buf 0 (A: 2 issues of 128 rows; B: 1 issue)
#pragma unroll
  for (int j = 0; j < 2; ++j)
    gload16(&A[(size_t)(brow + j * 128 + srow) * D_ + schk],
            &As[(j * 128 + wid * 16) * 32]);
  gload16(&Bt[(size_t)(bcol + srow) * D_ + schk], &Bs[(wid * 16) * 32]);

  const int NIT = D_ / 32;
  for (int t = 0; t < NIT; ++t) {
    const int cur = t & 1;
    asm volatile("s_barrier" ::: "memory");        // A: buf[cur^1] released
    __builtin_amdgcn_sched_barrier(0);
    if (t + 1 < NIT) {
      const int kk = (t + 1) * 32;
#pragma unroll
      for (int j = 0; j < 2; ++j)
        gload16(&A[(size_t)(brow + j * 128 + srow) * D_ + kk + schk],
                &As[(cur ^ 1) * 8192 + (j * 128 + wid * 16) * 32]);
      gload16(&Bt[(size_t)(bcol + srow) * D_ + kk + schk],
              &Bs[(cur ^ 1) * 4096 + (wid * 16) * 32]);
      asm volatile("s_waitcnt vmcnt(3)" ::: "memory");   // tile t resident
    } else {
      asm volatile("s_waitcnt vmcnt(0)" ::: "memory");
    }
    asm volatile("s_barrier" ::: "memory");        // B: buf[cur] resident
    __builtin_amdgcn_sched_barrier(0);

    const bf16* Ac = &As[cur * 8192];
    const bf16* Bc = &Bs[cur * 4096];
    bf16x8 af[4], bfr[4];
#pragma unroll
    for (int m = 0; m < 4; ++m)
      af[m] = *reinterpret_cast<const bf16x8*>(&Ac[(wr + m * 16 + l15) * 32 + q8]);
#pragma unroll
    for (int n = 0; n < 4; ++n)
      bfr[n] = *reinterpret_cast<const bf16x8*>(&Bc[(wc + n * 16 + l15) * 32 + q8]);
#pragma unroll
    for (int m = 0; m < 4; ++m)
#pragma unroll
      for (int n = 0; n < 4; ++n)
        acc[m][n] = __builtin_amdgcn_mfma_f32_16x16x32_bf16(af[m], bfr[n],
                                                            acc[m][n], 0, 0, 0);
  }

  const int which = bcol >> 10;   // 0:Q 1:K 2:V (block-uniform)
  const int r0 = g * 4;
  if (which == 2) {
    // V^T: rows (b*H+h)*64+hd, cols nn; r is nn-contiguous -> pack bf16x4
#pragma unroll
    for (int m = 0; m < 4; ++m)
#pragma unroll
      for (int n = 0; n < 4; ++n) {
        int nn0  = brow + wr + m * 16 + r0;        // 4 consecutive nn
        int gcol = (bcol & 1023) + wc + n * 16 + l15;
        int b = nn0 >> 11, nn = nn0 & (N_ - 1);
        int h = gcol >> 6, hd = gcol & 63;
        bf16x4 o;
#pragma unroll
        for (int r = 0; r < 4; ++r) o[r] = (bf16)acc[m][n][r];
        *reinterpret_cast<bf16x4*>(
            &vtb[((size_t)((b * H_ + h) * HD_ + hd)) * N_ + nn]) = o;
      }
  } else {
    bf16* outp = (which == 0) ? qb : kb;
#pragma unroll
    for (int m = 0; m < 4; ++m)
#pragma unroll
      for (int n = 0; n < 4; ++n)
#pragma unroll
        for (int r = 0; r < 4; ++r) {
          int grow = brow + wr + m * 16 + r0 + r;
          int gcol = (bcol & 1023) + wc + n * 16 + l15;
          int b = grow >> 11, nn = grow & (N_ - 1);
          int h = gcol >> 6, hd = gcol & 63;
          outp[((((size_t)(b * H_ + h)) * N_ + nn) << 6) + hd] = (bf16)acc[m][n][r];
        }
  }
}

// ---------------- output GEMM: out[M,D] = ctx[M,D] x Wo[D,D]^T + bo ------------
// (unchanged round-13 structure: 128^2, triple-buffered depth-2 counted vmcnt)
__global__ __launch_bounds__(256, 3)
void gemm_out(const bf16* __restrict__ A, const bf16* __restrict__ Bt,
              float* __restrict__ C, const float* __restrict__ bias)
{
  __shared__ bf16 As[3 * 128 * 32];
  __shared__ bf16 Bs[3 * 128 * 32];
  const int tid  = threadIdx.x;
  const int lane = tid & 63;
  const int wid  = tid >> 6;
  const int wg   = blockIdx.x;
  const int xcd  = wg & 7;
  const int idx  = wg >> 3;                 // 0..63
  const int brow = ((xcd << 3) + (idx & 7)) * 128;
  const int bcol = (idx >> 3) * 128;        // 0..7 blocks
  const int wr   = (wid >> 1) * 64;
  const int wc   = (wid & 1) * 64;
  const int l15  = lane & 15;
  const int g    = lane >> 4;

  f32x4 acc[4][4] = {};
  const int srow = wid * 16 + (lane >> 2);
  const int schk = ((lane & 3) ^ ((lane >> 4) & 3)) * 8;
  const int q8   = ((lane >> 4) ^ (l15 >> 2)) * 8;
#pragma unroll
  for (int j = 0; j < 2; ++j) {
    gload16(&A[(size_t)(brow + j * 64 + srow) * D_ + schk],
            &As[(j * 64 + wid * 16) * 32]);
    gload16(&Bt[(size_t)(bcol + j * 64 + srow) * D_ + schk],
            &Bs[(j * 64 + wid * 16) * 32]);
  }
#pragma unroll
  for (int j = 0; j < 2; ++j) {
    gload16(&A[(size_t)(brow + j * 64 + srow) * D_ + 32 + schk],
            &As[4096 + (j * 64 + wid * 16) * 32]);
    gload16(&Bt[(size_t)(bcol + j * 64 + srow) * D_ + 32 + schk],
            &Bs[4096 + (j * 64 + wid * 16) * 32]);
  }
  const int NIT = D_ / 32;
  int cur = 0, pre = 2;
  for (int t = 0; t < NIT; ++t) {
    asm volatile("s_barrier" ::: "memory");
    __builtin_amdgcn_sched_barrier(0);
    if (t + 2 < NIT) {
      const int kk = (t + 2) * 32;
#pragma unroll
      for (int j = 0; j < 2; ++j) {
        gload16(&A[(size_t)(brow + j * 64 + srow) * D_ + kk + schk],
                &As[pre * 4096 + (j * 64 + wid * 16) * 32]);
        gload16(&Bt[(size_t)(bcol + j * 64 + srow) * D_ + kk + schk],
                &Bs[pre * 4096 + (j * 64 + wid * 16) * 32]);
      }
      asm volatile("s_waitcnt vmcnt(8)" ::: "memory");
    } else if (t + 1 < NIT) {
      asm volatile("s_waitcnt vmcnt(4)" ::: "memory");
    } else {
      asm volatile("s_waitcnt vmcnt(0)" ::: "memory");
    }
    asm volatile("s_barrier" ::: "memory");
    __builtin_amdgcn_sched_barrier(0);
    const bf16* Ac = &As[cur * 4096];
    const bf16* Bc = &Bs[cur * 4096];
    bf16x8 af[4], bfr[4];
#pragma unroll
    for (int m = 0; m < 4; ++m)
      af[m] = *reinterpret_cast<const bf16x8*>(&Ac[(wr + m * 16 + l15) * 32 + q8]);
#pragma unroll
    for (int n = 0; n < 4; ++n)
      bfr[n] = *reinterpret_cast<const bf16x8*>(&Bc[(wc + n * 16 + l15) * 32 + q8]);
#pragma unroll
    for (int m = 0; m < 4; ++m)
#pragma unroll
      for (int n = 0; n < 4; ++n)
        acc[m][n] = __builtin_amdgcn_mfma_f32_16x16x32_bf16(af[m], bfr[n],
                                                            acc[m][n], 0, 0, 0);
    cur = (cur == 2) ? 0 : cur + 1;
    pre = (pre == 2) ? 0 : pre + 1;
  }

  const int r0 = g * 4;
#pragma unroll
  for (int m = 0; m < 4; ++m)
#pragma unroll
    for (int n = 0; n < 4; ++n)
#pragma unroll
      for (int r = 0; r < 4; ++r) {
        int grow = brow + wr + m * 16 + r0 + r;
        int gcol = bcol + wc + n * 16 + l15;
        C[(size_t)grow * D_ + gcol] = acc[m][n][r] + bias[gcol];
      }
}

// ---------------- fused causal flash attention: 4-wave, 32 q-rows/wave ---------
// (round-14 structure; only change: exp2f -> raw v_exp_f32)
__global__ __launch_bounds__(256, 3)
void attn_k(const bf16* __restrict__ q, const bf16* __restrict__ k,
            const bf16* __restrict__ vt, bf16* __restrict__ ctx)
{
  __shared__ bf16 Ks[2][64 * 64];
  __shared__ bf16 Vs[2][64 * 64];
  __shared__ bf16 Pl[4][2][16][72];   // 16 q x 64 keys + 8 pad (DO NOT SHRINK)
  const int tid  = threadIdx.x;
  const int lane = tid & 63;
  const int wid  = tid >> 6;          // 0..3
  const int bid  = blockIdx.x;
  const int bh   = bid & 63;
  const int c    = 15 - (bid >> 6);   // q-chunk 0..15, heavy-first
  const int l15  = lane & 15;
  const int g    = lane >> 4;
  const int lk   = g * 8;
  const int swz  = (l15 & 7) << 4;    // read-side XOR swizzle (bytes)

  const bf16* kp = k  + (size_t)bh * N_ * HD_;
  const bf16* vp = vt + (size_t)bh * HD_ * N_;
  const int b = bh >> 4, h = bh & 15;

  const int sr8   = lane >> 3;
  const int scoff = ((lane & 7) ^ sr8) * 8;    // elems

  bf16x8 ones8;
#pragma unroll
  for (int i = 0; i < 8; ++i) ones8[i] = (bf16)1.0f;

  const int qbase = c * 128 + wid * 32;     // wave owns rows qbase..qbase+31
  const int nt    = 2 * c + 2;              // KV tiles for this block
  const int tm    = 2 * c + (wid >> 1);     // wave's diagonal tile

  const bf16* qp = q + ((size_t)bh * N_ + qbase) * HD_;
  bf16x8 aq[2][2];
#pragma unroll
  for (int m = 0; m < 2; ++m)
#pragma unroll
    for (int c2 = 0; c2 < 2; ++c2)
      aq[m][c2] = ld8(qp + (size_t)(m * 16 + l15) * HD_ + c2 * 32 + lk);

  f32x4 oacc[2][5] = {};    // [m][0..3]: O^T d-tiles; [m][4]: l (ones-row PV)

  // prologue: stage tile 0 into buf 0 (4 loads/wave)
#pragma unroll
  for (int j = 0; j < 2; ++j) {
    const int rr = j * 32 + wid * 8 + sr8;
    gload16(kp + (size_t)rr * HD_ + scoff, &Ks[0][(j * 32 + wid * 8) * 64]);
    gload16(vp + (size_t)rr * N_ + scoff, &Vs[0][(j * 32 + wid * 8) * 64]);
  }

  for (int t = 0; t < nt; ++t) {
    const int cur = t & 1;
    asm volatile("s_barrier" ::: "memory");        // A: buf[cur^1] released
    __builtin_amdgcn_sched_barrier(0);
    if (t + 1 < nt) {
      const int kb = (t + 1) * 64;
#pragma unroll
      for (int j = 0; j < 2; ++j) {
        const int rr = j * 32 + wid * 8 + sr8;
        gload16(kp + (size_t)(kb + rr) * HD_ + scoff,
                &Ks[cur ^ 1][(j * 32 + wid * 8) * 64]);
        gload16(vp + (size_t)rr * N_ + kb + scoff,
                &Vs[cur ^ 1][(j * 32 + wid * 8) * 64]);
      }
      asm volatile("s_waitcnt vmcnt(4)" ::: "memory");   // tile t resident
    } else {
      asm volatile("s_waitcnt vmcnt(0)" ::: "memory");
    }
    asm volatile("s_barrier" ::: "memory");        // B: buf[cur] resident
    __builtin_amdgcn_sched_barrier(0);

    if (t <= tm) {      // wave-uniform: tiles with unmasked keys only
      const char* kb_ = (const char*)&Ks[cur][0];
      const char* vb_ = (const char*)&Vs[cur][0];

      // QK^T (swapped): S^T[key][q], A = K rows, B = Q cols; K frags shared by m
      f32x4 s[2][4] = {};
#pragma unroll
      for (int tt = 0; tt < 4; ++tt) {
        bf16x8 bk0 = *reinterpret_cast<const bf16x8*>(
            kb_ + (tt * 16 + l15) * 128 + ((g * 16) ^ swz));
        bf16x8 bk1 = *reinterpret_cast<const bf16x8*>(
            kb_ + (tt * 16 + l15) * 128 + ((64 + g * 16) ^ swz));
#pragma unroll
        for (int m = 0; m < 2; ++m) {
          s[m][tt] = __builtin_amdgcn_mfma_f32_16x16x32_bf16(bk0, aq[m][0], s[m][tt], 0, 0, 0);
          s[m][tt] = __builtin_amdgcn_mfma_f32_16x16x32_bf16(bk1, aq[m][1], s[m][tt], 0, 0, 0);
        }
      }

      if (t == tm) {    // causal mask on the wave's diagonal tile
#pragma unroll
        for (int m = 0; m < 2; ++m) {
          const int qr = qbase + m * 16 + l15;
#pragma unroll
          for (int tt = 0; tt < 4; ++tt)
#pragma unroll
            for (int r = 0; r < 4; ++r) {
              int kq = t * 64 + tt * 16 + g * 4 + r;
              if (kq > qr) s[m][tt][r] = -1e30f;
            }
        }
      }

      // no-max softmax: p = exp2(s) via raw v_exp_f32; masked -> 0
#pragma unroll
      for (int m = 0; m < 2; ++m) {
#pragma unroll
        for (int tt = 0; tt < 4; ++tt)
#pragma unroll
          for (int r = 0; r < 4; ++r) s[m][tt][r] = exp2_raw(s[m][tt][r]);

        // P[q][key] -> per-wave LDS (C-layout -> B-layout transpose)
#pragma unroll
        for (int tt = 0; tt < 4; ++tt) {
          bf16x4 pk;
#pragma unroll
          for (int r = 0; r < 4; ++r) pk[r] = (bf16)s[m][tt][r];
          *reinterpret_cast<bf16x4*>(&Pl[wid][m][l15][tt * 16 + g * 4]) = pk;
        }
      }

      // PV: O^T += V^T(LDS) * P; l += ones * P.  V frags shared by both m.
#pragma unroll
      for (int kc = 0; kc < 2; ++kc) {
        bf16x8 pb[2];
#pragma unroll
        for (int m = 0; m < 2; ++m)
          pb[m] = *reinterpret_cast<const bf16x8*>(&Pl[wid][m][l15][kc * 32 + lk]);
#pragma unroll
        for (int n = 0; n < 4; ++n) {
          bf16x8 vf = *reinterpret_cast<const bf16x8*>(
              vb_ + (n * 16 + l15) * 128 + ((kc * 64 + g * 16) ^ swz));
#pragma unroll
          for (int m = 0; m < 2; ++m)
            oacc[m][n] = __builtin_amdgcn_mfma_f32_16x16x32_bf16(vf, pb[m], oacc[m][n], 0, 0, 0);
        }
#pragma unroll
        for (int m = 0; m < 2; ++m)
          oacc[m][4] = __builtin_amdgcn_mfma_f32_16x16x32_bf16(ones8, pb[m], oacc[m][4], 0, 0, 0);
      }
    }
  }

  // epilogue: lane owns queries qbase + m*16 + l15; d = n*16 + g*4 + r
#pragma unroll
  for (int m = 0; m < 2; ++m) {
    float inv = 1.f / oacc[m][4][0];
    bf16* cp = ctx + ((size_t)b * N_ + qbase + m * 16 + l15) * D_ + h * HD_;
#pragma unroll
    for (int n = 0; n < 4; ++n) {
      bf16x4 o;
#pragma unroll
      for (int r = 0; r < 4; ++r) o[r] = (bf16)(oacc[m][n][r] * inv);
      *reinterpret_cast<bf16x4*>(cp + n * 16 + g * 4) = o;
    }
  }
}

// ---------------- launcher ----------------------------------------------------
extern "C" void kernel_launch(void* const* d_in, const int* in_sizes, int n_in,
                              void* d_out, int out_size, void* d_ws, size_t ws_size,
                              hipStream_t stream)
{
  const float* x  = (const float*)d_in[0];
  const float* Wq = (const float*)d_in[1];
  const float* Wk = (const float*)d_in[2];
  const float* Wv = (const float*)d_in[3];
  const float* Wo = (const float*)d_in[4];
  const float* bo = (const float*)d_in[5];
  float* out = (float*)d_out;

  const size_t SZ_BHND = (size_t)B_ * H_ * N_ * HD_ * sizeof(bf16); // 16 MiB
  const size_t SZ_W    = (size_t)D_ * D_ * sizeof(bf16);            // 2 MiB
  char* ws = (char*)d_ws;
  bf16* xbf  = (bf16*)(ws);                    // reused as ctx after QKV gemm
  bf16* ctx  = (bf16*)(ws);
  bf16* qb   = (bf16*)(ws + SZ_BHND);
  bf16* kbf  = (bf16*)(ws + 2 * SZ_BHND);
  bf16* vtb  = (bf16*)(ws + 3 * SZ_BHND);
  bf16* wqkv = (bf16*)(ws + 4 * SZ_BHND);      // [3072][1024]
  bf16* wob  = (bf16*)(ws + 4 * SZ_BHND + 3 * SZ_W);
  if (ws_size < 4 * SZ_BHND + 4 * SZ_W) return;

  const int NX = B_ * N_ * D_;      // 8M
  cast_k<<<NX / (256 * 8), 256, 0, stream>>>(x, xbf, NX);
  cast_k<<<(D_ * D_) / (256 * 8), 256, 0, stream>>>(Wo, wob, D_ * D_);

  transpose3_k<<<dim3(32, 32, 3), dim3(32, 32), 0, stream>>>(Wq, Wk, Wv, wqkv);

  gemm_qkv<<<768, 512, 0, stream>>>(xbf, wqkv, qb, kbf, vtb);

  attn_k<<<1024, 256, 0, stream>>>(qb, kbf, vtb, ctx);

  gemm_out<<<512, 256, 0, stream>>>(ctx, wob, out, bo);
}

// Round 16
// 156.554 us; speedup vs baseline: 2.2505x; 2.2505x over previous
//
#include <hip/hip_runtime.h>
#include <hip/hip_bf16.h>

typedef __bf16 bf16;
typedef __bf16 bf16x4 __attribute__((ext_vector_type(4)));
typedef __bf16 bf16x8 __attribute__((ext_vector_type(8)));
typedef float  f32x4  __attribute__((ext_vector_type(4)));

#define B_  4
#define N_  2048
#define D_  1024
#define H_  16
#define HD_ 64

// 0.125 (1/sqrt(64)) * log2(e): folded into Wq during transpose
#define QSCALE 0.1803368801111204f

__device__ __forceinline__ bf16x8 ld8(const bf16* p) {
  return *reinterpret_cast<const bf16x8*>(p);
}

// raw v_exp_f32 (2^x): no denormal-fixup sequence; -1e30 -> 0, handled in HW
__device__ __forceinline__ float exp2_raw(float x) {
  float y;
  asm("v_exp_f32 %0, %1" : "=v"(y) : "v"(x));
  return y;
}

// async global->LDS, 16B per lane; lds base must be wave-uniform
__device__ __forceinline__ void gload16(const bf16* g, bf16* l) {
  __builtin_amdgcn_global_load_lds(
      (const __attribute__((address_space(1))) void*)g,
      (__attribute__((address_space(3))) void*)l, 16, 0, 0);
}

// ---------------- f32 -> bf16 cast (8 elems/thread) ----------------------------
__global__ __launch_bounds__(256) void cast_k(const float* __restrict__ in,
                                              bf16* __restrict__ out, int n) {
  int i = (blockIdx.x * 256 + threadIdx.x) * 8;
  if (i >= n) return;
  float4 a = *reinterpret_cast<const float4*>(in + i);
  float4 b = *reinterpret_cast<const float4*>(in + i + 4);
  bf16x8 o;
  o[0] = (bf16)a.x; o[1] = (bf16)a.y; o[2] = (bf16)a.z; o[3] = (bf16)a.w;
  o[4] = (bf16)b.x; o[5] = (bf16)b.y; o[6] = (bf16)b.z; o[7] = (bf16)b.w;
  *reinterpret_cast<bf16x8*>(out + i) = o;
}

// ---- fused transpose-cast of Wq/Wk/Wv (z selects): out[z][c][r] = s*in[z][r][c]
__global__ __launch_bounds__(1024)
void transpose3_k(const float* __restrict__ w0, const float* __restrict__ w1,
                  const float* __restrict__ w2, bf16* __restrict__ out) {
  __shared__ float t[32][33];
  const int z = blockIdx.z;
  const float* in = (z == 0) ? w0 : (z == 1) ? w1 : w2;
  const float scale = (z == 0) ? QSCALE : 1.0f;
  bf16* o = out + (size_t)z * D_ * D_;
  int c = blockIdx.x * 32 + threadIdx.x;
  int r = blockIdx.y * 32 + threadIdx.y;
  t[threadIdx.y][threadIdx.x] = in[r * D_ + c];
  __syncthreads();
  int oc = blockIdx.y * 32 + threadIdx.x;
  int orr = blockIdx.x * 32 + threadIdx.y;
  o[orr * D_ + oc] = (bf16)(scale * t[threadIdx.x][threadIdx.y]);
}

// ---- GEMM core (PROVEN r14): BK=32, 128x128 tile, TRIPLE-buffered depth-2
// prefetch, counted vmcnt. Per iter: barrierA (buf[pre] free) -> stage(t+2) ->
// vmcnt(8) -> barrierB -> compute(t). Epilogue drains 8->4->0.
// DO NOT change tile geometry: r10 (BK=64) and r15 (256x128) both regressed —
// this 1536-block/128^2 layout is what keeps per-XCD working set inside 4MB L2.
#define GEMM_CORE(A_, Bt_, K_)                                                    \
  f32x4 acc[4][4] = {};                                                           \
  const int srow = wid * 16 + (lane >> 2);          /* staged row (+j*64) */      \
  const int schk = ((lane & 3) ^ ((lane >> 4) & 3)) * 8;  /* swz src col */       \
  const int q8   = ((lane >> 4) ^ (l15 >> 2)) * 8;  /* swz read col */            \
  _Pragma("unroll")                                                               \
  for (int j = 0; j < 2; ++j) {                                                   \
    gload16(&(A_)[(size_t)(brow + j * 64 + srow) * (K_) + schk],                  \
            &As[(j * 64 + wid * 16) * 32]);                                       \
    gload16(&(Bt_)[(size_t)(bcol + j * 64 + srow) * (K_) + schk],                 \
            &Bs[(j * 64 + wid * 16) * 32]);                                       \
  }                                                                               \
  _Pragma("unroll")                                                               \
  for (int j = 0; j < 2; ++j) {                                                   \
    gload16(&(A_)[(size_t)(brow + j * 64 + srow) * (K_) + 32 + schk],             \
            &As[4096 + (j * 64 + wid * 16) * 32]);                                \
    gload16(&(Bt_)[(size_t)(bcol + j * 64 + srow) * (K_) + 32 + schk],            \
            &Bs[4096 + (j * 64 + wid * 16) * 32]);                                \
  }                                                                               \
  const int NIT = (K_) / 32;                                                      \
  int cur = 0, pre = 2;                                                           \
  for (int t = 0; t < NIT; ++t) {                                                 \
    asm volatile("s_barrier" ::: "memory");       /* A: buf[pre] released */      \
    __builtin_amdgcn_sched_barrier(0);                                            \
    if (t + 2 < NIT) {                                                            \
      const int kk = (t + 2) * 32;                                                \
      _Pragma("unroll")                                                           \
      for (int j = 0; j < 2; ++j) {                                               \
        gload16(&(A_)[(size_t)(brow + j * 64 + srow) * (K_) + kk + schk],         \
                &As[pre * 4096 + (j * 64 + wid * 16) * 32]);                      \
        gload16(&(Bt_)[(size_t)(bcol + j * 64 + srow) * (K_) + kk + schk],        \
                &Bs[pre * 4096 + (j * 64 + wid * 16) * 32]);                      \
      }                                                                           \
      asm volatile("s_waitcnt vmcnt(8)" ::: "memory");                            \
    } else if (t + 1 < NIT) {                                                     \
      asm volatile("s_waitcnt vmcnt(4)" ::: "memory");                            \
    } else {                                                                      \
      asm volatile("s_waitcnt vmcnt(0)" ::: "memory");                            \
    }                                                                             \
    asm volatile("s_barrier" ::: "memory");       /* B: buf[cur] resident */      \
    __builtin_amdgcn_sched_barrier(0);                                            \
    const bf16* Ac = &As[cur * 4096];                                             \
    const bf16* Bc = &Bs[cur * 4096];                                             \
    bf16x8 af[4], bfr[4];                                                         \
    _Pragma("unroll")                                                             \
    for (int m = 0; m < 4; ++m)                                                   \
      af[m] = *reinterpret_cast<const bf16x8*>(&Ac[(wr + m * 16 + l15) * 32 + q8]); \
    _Pragma("unroll")                                                             \
    for (int n = 0; n < 4; ++n)                                                   \
      bfr[n] = *reinterpret_cast<const bf16x8*>(&Bc[(wc + n * 16 + l15) * 32 + q8]); \
    _Pragma("unroll")                                                             \
    for (int m = 0; m < 4; ++m)                                                   \
      _Pragma("unroll")                                                           \
      for (int n = 0; n < 4; ++n)                                                 \
        acc[m][n] = __builtin_amdgcn_mfma_f32_16x16x32_bf16(af[m], bfr[n],        \
                                                            acc[m][n], 0, 0, 0);  \
    cur = (cur == 2) ? 0 : cur + 1;                                               \
    pre = (pre == 2) ? 0 : pre + 1;                                               \
  }

// ---------------- fused QKV GEMM: [8192,1024] x [3072,1024]^T ------------------
__global__ __launch_bounds__(256, 3)
void gemm_qkv(const bf16* __restrict__ A, const bf16* __restrict__ Bt,
              bf16* __restrict__ qb, bf16* __restrict__ kb, bf16* __restrict__ vtb)
{
  __shared__ bf16 As[3 * 128 * 32];
  __shared__ bf16 Bs[3 * 128 * 32];
  const int tid  = threadIdx.x;
  const int lane = tid & 63;
  const int wid  = tid >> 6;
  const int wg   = blockIdx.x;
  const int xcd  = wg & 7;
  const int idx  = wg >> 3;                 // 0..191
  const int brow = ((xcd << 3) + (idx & 7)) * 128;
  const int bcol = (idx >> 3) * 128;        // 0..23 blocks
  const int wr   = (wid >> 1) * 64;
  const int wc   = (wid & 1) * 64;
  const int l15  = lane & 15;
  const int g    = lane >> 4;

  GEMM_CORE(A, Bt, D_)

  const int which = bcol >> 10;   // 0:Q 1:K 2:V (block-uniform)
  const int r0 = g * 4;
  if (which == 2) {
    // V^T: rows (b*H+h)*64+hd, cols nn; r is nn-contiguous -> pack bf16x4
#pragma unroll
    for (int m = 0; m < 4; ++m)
#pragma unroll
      for (int n = 0; n < 4; ++n) {
        int nn0  = brow + wr + m * 16 + r0;        // 4 consecutive nn
        int gcol = (bcol & 1023) + wc + n * 16 + l15;
        int b = nn0 >> 11, nn = nn0 & (N_ - 1);
        int h = gcol >> 6, hd = gcol & 63;
        bf16x4 o;
#pragma unroll
        for (int r = 0; r < 4; ++r) o[r] = (bf16)acc[m][n][r];
        *reinterpret_cast<bf16x4*>(
            &vtb[((size_t)((b * H_ + h) * HD_ + hd)) * N_ + nn]) = o;
      }
  } else {
    bf16* outp = (which == 0) ? qb : kb;
#pragma unroll
    for (int m = 0; m < 4; ++m)
#pragma unroll
      for (int n = 0; n < 4; ++n)
#pragma unroll
        for (int r = 0; r < 4; ++r) {
          int grow = brow + wr + m * 16 + r0 + r;
          int gcol = (bcol & 1023) + wc + n * 16 + l15;
          int b = grow >> 11, nn = grow & (N_ - 1);
          int h = gcol >> 6, hd = gcol & 63;
          outp[((((size_t)(b * H_ + h)) * N_ + nn) << 6) + hd] = (bf16)acc[m][n][r];
        }
  }
}

// ---------------- output GEMM: out[M,D] = ctx[M,D] x Wo[D,D]^T + bo ------------
__global__ __launch_bounds__(256, 3)
void gemm_out(const bf16* __restrict__ A, const bf16* __restrict__ Bt,
              float* __restrict__ C, const float* __restrict__ bias)
{
  __shared__ bf16 As[3 * 128 * 32];
  __shared__ bf16 Bs[3 * 128 * 32];
  const int tid  = threadIdx.x;
  const int lane = tid & 63;
  const int wid  = tid >> 6;
  const int wg   = blockIdx.x;
  const int xcd  = wg & 7;
  const int idx  = wg >> 3;                 // 0..63
  const int brow = ((xcd << 3) + (idx & 7)) * 128;
  const int bcol = (idx >> 3) * 128;        // 0..7 blocks
  const int wr   = (wid >> 1) * 64;
  const int wc   = (wid & 1) * 64;
  const int l15  = lane & 15;
  const int g    = lane >> 4;

  GEMM_CORE(A, Bt, D_)

  const int r0 = g * 4;
#pragma unroll
  for (int m = 0; m < 4; ++m)
#pragma unroll
    for (int n = 0; n < 4; ++n)
#pragma unroll
      for (int r = 0; r < 4; ++r) {
        int grow = brow + wr + m * 16 + r0 + r;
        int gcol = bcol + wc + n * 16 + l15;
        C[(size_t)grow * D_ + gcol] = acc[m][n][r] + bias[gcol];
      }
}

// ---------------- fused causal flash attention: 4-wave, 32 q-rows/wave ---------
// (round-14 structure + raw v_exp_f32)
__global__ __launch_bounds__(256, 3)
void attn_k(const bf16* __restrict__ q, const bf16* __restrict__ k,
            const bf16* __restrict__ vt, bf16* __restrict__ ctx)
{
  __shared__ bf16 Ks[2][64 * 64];
  __shared__ bf16 Vs[2][64 * 64];
  __shared__ bf16 Pl[4][2][16][72];   // 16 q x 64 keys + 8 pad (DO NOT SHRINK)
  const int tid  = threadIdx.x;
  const int lane = tid & 63;
  const int wid  = tid >> 6;          // 0..3
  const int bid  = blockIdx.x;
  const int bh   = bid & 63;
  const int c    = 15 - (bid >> 6);   // q-chunk 0..15, heavy-first
  const int l15  = lane & 15;
  const int g    = lane >> 4;
  const int lk   = g * 8;
  const int swz  = (l15 & 7) << 4;    // read-side XOR swizzle (bytes)

  const bf16* kp = k  + (size_t)bh * N_ * HD_;
  const bf16* vp = vt + (size_t)bh * HD_ * N_;
  const int b = bh >> 4, h = bh & 15;

  const int sr8   = lane >> 3;
  const int scoff = ((lane & 7) ^ sr8) * 8;    // elems

  bf16x8 ones8;
#pragma unroll
  for (int i = 0; i < 8; ++i) ones8[i] = (bf16)1.0f;

  const int qbase = c * 128 + wid * 32;     // wave owns rows qbase..qbase+31
  const int nt    = 2 * c + 2;              // KV tiles for this block
  const int tm    = 2 * c + (wid >> 1);     // wave's diagonal tile

  const bf16* qp = q + ((size_t)bh * N_ + qbase) * HD_;
  bf16x8 aq[2][2];
#pragma unroll
  for (int m = 0; m < 2; ++m)
#pragma unroll
    for (int c2 = 0; c2 < 2; ++c2)
      aq[m][c2] = ld8(qp + (size_t)(m * 16 + l15) * HD_ + c2 * 32 + lk);

  f32x4 oacc[2][5] = {};    // [m][0..3]: O^T d-tiles; [m][4]: l (ones-row PV)

  // prologue: stage tile 0 into buf 0 (4 loads/wave)
#pragma unroll
  for (int j = 0; j < 2; ++j) {
    const int rr = j * 32 + wid * 8 + sr8;
    gload16(kp + (size_t)rr * HD_ + scoff, &Ks[0][(j * 32 + wid * 8) * 64]);
    gload16(vp + (size_t)rr * N_ + scoff, &Vs[0][(j * 32 + wid * 8) * 64]);
  }

  for (int t = 0; t < nt; ++t) {
    const int cur = t & 1;
    asm volatile("s_barrier" ::: "memory");        // A: buf[cur^1] released
    __builtin_amdgcn_sched_barrier(0);
    if (t + 1 < nt) {
      const int kb = (t + 1) * 64;
#pragma unroll
      for (int j = 0; j < 2; ++j) {
        const int rr = j * 32 + wid * 8 + sr8;
        gload16(kp + (size_t)(kb + rr) * HD_ + scoff,
                &Ks[cur ^ 1][(j * 32 + wid * 8) * 64]);
        gload16(vp + (size_t)rr * N_ + kb + scoff,
                &Vs[cur ^ 1][(j * 32 + wid * 8) * 64]);
      }
      asm volatile("s_waitcnt vmcnt(4)" ::: "memory");   // tile t resident
    } else {
      asm volatile("s_waitcnt vmcnt(0)" ::: "memory");
    }
    asm volatile("s_barrier" ::: "memory");        // B: buf[cur] resident
    __builtin_amdgcn_sched_barrier(0);

    if (t <= tm) {      // wave-uniform: tiles with unmasked keys only
      const char* kb_ = (const char*)&Ks[cur][0];
      const char* vb_ = (const char*)&Vs[cur][0];

      // QK^T (swapped): S^T[key][q], A = K rows, B = Q cols; K frags shared by m
      f32x4 s[2][4] = {};
#pragma unroll
      for (int tt = 0; tt < 4; ++tt) {
        bf16x8 bk0 = *reinterpret_cast<const bf16x8*>(
            kb_ + (tt * 16 + l15) * 128 + ((g * 16) ^ swz));
        bf16x8 bk1 = *reinterpret_cast<const bf16x8*>(
            kb_ + (tt * 16 + l15) * 128 + ((64 + g * 16) ^ swz));
#pragma unroll
        for (int m = 0; m < 2; ++m) {
          s[m][tt] = __builtin_amdgcn_mfma_f32_16x16x32_bf16(bk0, aq[m][0], s[m][tt], 0, 0, 0);
          s[m][tt] = __builtin_amdgcn_mfma_f32_16x16x32_bf16(bk1, aq[m][1], s[m][tt], 0, 0, 0);
        }
      }

      if (t == tm) {    // causal mask on the wave's diagonal tile
#pragma unroll
        for (int m = 0; m < 2; ++m) {
          const int qr = qbase + m * 16 + l15;
#pragma unroll
          for (int tt = 0; tt < 4; ++tt)
#pragma unroll
            for (int r = 0; r < 4; ++r) {
              int kq = t * 64 + tt * 16 + g * 4 + r;
              if (kq > qr) s[m][tt][r] = -1e30f;
            }
        }
      }

      // no-max softmax: p = exp2(s) via raw v_exp_f32; masked -> 0
#pragma unroll
      for (int m = 0; m < 2; ++m) {
#pragma unroll
        for (int tt = 0; tt < 4; ++tt)
#pragma unroll
          for (int r = 0; r < 4; ++r) s[m][tt][r] = exp2_raw(s[m][tt][r]);

        // P[q][key] -> per-wave LDS (C-layout -> B-layout transpose)
#pragma unroll
        for (int tt = 0; tt < 4; ++tt) {
          bf16x4 pk;
#pragma unroll
          for (int r = 0; r < 4; ++r) pk[r] = (bf16)s[m][tt][r];
          *reinterpret_cast<bf16x4*>(&Pl[wid][m][l15][tt * 16 + g * 4]) = pk;
        }
      }

      // PV: O^T += V^T(LDS) * P; l += ones * P.  V frags shared by both m.
#pragma unroll
      for (int kc = 0; kc < 2; ++kc) {
        bf16x8 pb[2];
#pragma unroll
        for (int m = 0; m < 2; ++m)
          pb[m] = *reinterpret_cast<const bf16x8*>(&Pl[wid][m][l15][kc * 32 + lk]);
#pragma unroll
        for (int n = 0; n < 4; ++n) {
          bf16x8 vf = *reinterpret_cast<const bf16x8*>(
              vb_ + (n * 16 + l15) * 128 + ((kc * 64 + g * 16) ^ swz));
#pragma unroll
          for (int m = 0; m < 2; ++m)
            oacc[m][n] = __builtin_amdgcn_mfma_f32_16x16x32_bf16(vf, pb[m], oacc[m][n], 0, 0, 0);
        }
#pragma unroll
        for (int m = 0; m < 2; ++m)
          oacc[m][4] = __builtin_amdgcn_mfma_f32_16x16x32_bf16(ones8, pb[m], oacc[m][4], 0, 0, 0);
      }
    }
  }

  // epilogue: lane owns queries qbase + m*16 + l15; d = n*16 + g*4 + r
#pragma unroll
  for (int m = 0; m < 2; ++m) {
    float inv = 1.f / oacc[m][4][0];
    bf16* cp = ctx + ((size_t)b * N_ + qbase + m * 16 + l15) * D_ + h * HD_;
#pragma unroll
    for (int n = 0; n < 4; ++n) {
      bf16x4 o;
#pragma unroll
      for (int r = 0; r < 4; ++r) o[r] = (bf16)(oacc[m][n][r] * inv);
      *reinterpret_cast<bf16x4*>(cp + n * 16 + g * 4) = o;
    }
  }
}

// ---------------- launcher ----------------------------------------------------
extern "C" void kernel_launch(void* const* d_in, const int* in_sizes, int n_in,
                              void* d_out, int out_size, void* d_ws, size_t ws_size,
                              hipStream_t stream)
{
  const float* x  = (const float*)d_in[0];
  const float* Wq = (const float*)d_in[1];
  const float* Wk = (const float*)d_in[2];
  const float* Wv = (const float*)d_in[3];
  const float* Wo = (const float*)d_in[4];
  const float* bo = (const float*)d_in[5];
  float* out = (float*)d_out;

  const size_t SZ_BHND = (size_t)B_ * H_ * N_ * HD_ * sizeof(bf16); // 16 MiB
  const size_t SZ_W    = (size_t)D_ * D_ * sizeof(bf16);            // 2 MiB
  char* ws = (char*)d_ws;
  bf16* xbf  = (bf16*)(ws);                    // reused as ctx after QKV gemm
  bf16* ctx  = (bf16*)(ws);
  bf16* qb   = (bf16*)(ws + SZ_BHND);
  bf16* kbf  = (bf16*)(ws + 2 * SZ_BHND);
  bf16* vtb  = (bf16*)(ws + 3 * SZ_BHND);
  bf16* wqkv = (bf16*)(ws + 4 * SZ_BHND);      // [3072][1024]
  bf16* wob  = (bf16*)(ws + 4 * SZ_BHND + 3 * SZ_W);
  if (ws_size < 4 * SZ_BHND + 4 * SZ_W) return;

  const int NX = B_ * N_ * D_;      // 8M
  cast_k<<<NX / (256 * 8), 256, 0, stream>>>(x, xbf, NX);
  cast_k<<<(D_ * D_) / (256 * 8), 256, 0, stream>>>(Wo, wob, D_ * D_);

  transpose3_k<<<dim3(32, 32, 3), dim3(32, 32), 0, stream>>>(Wq, Wk, Wv, wqkv);

  gemm_qkv<<<1536, 256, 0, stream>>>(xbf, wqkv, qb, kbf, vtb);

  attn_k<<<1024, 256, 0, stream>>>(qb, kbf, vtb, ctx);

  gemm_out<<<512, 256, 0, stream>>>(ctx, wob, out, bo);
}